// Round 7
// baseline (188.543 us; speedup 1.0000x reference)
//
#include <hip/hip_runtime.h>
#include <hip/hip_bf16.h>
#include <math.h>

// B=4, T=4096, C=1024, H=64. fp32 in/out, bf16 MFMA internally.
// memset: zero accp (fp32 accumulator [BT][68], col 64 = l).
// K1 wtrans: W (C,H) fp32 -> WT bf16 [192][1024].
// K2 qkv_proj: M=64/block, grid 256, 512 thr; x+W LDS-staged, reg prefetch.
// K3 attn (round 7 rewrite): BARRIER-FREE K-loop. Each wave independently
//     walks its kt tiles; K/V fragments loaded straight from global (L2).
//     S computed TRANSPOSED (mfma(ka,qa)) so P packs into b64 LDS writes;
//     P round-trips wave-private LDS into A-frag layout for PV.
//     l = sum(p) accumulated per-lane, 2 shfl_xor at the end. No ones-row.
// K4 normalize: out = acc[:, :64] / acc[:, 64].

#define BT   16384
#define TDIM 4096
#define CDIM 1024
#define HDIM 64
#define ACCW 68
#define QSCALE 0.18033688f   // 0.125 * log2(e)

typedef __attribute__((ext_vector_type(8))) short bf16x8;
typedef __attribute__((ext_vector_type(4))) float f32x4;
typedef __attribute__((ext_vector_type(8))) unsigned short us8;
typedef __attribute__((ext_vector_type(4))) unsigned short us4;

static __device__ __forceinline__ unsigned short f2bf(float f) {
    unsigned int u = __float_as_uint(f);
    u += 0x7fffu + ((u >> 16) & 1u);
    return (unsigned short)(u >> 16);
}

static __device__ __forceinline__ unsigned int pk2bf(float a, float b) {
    __hip_bfloat162 h = __float22bfloat162_rn(make_float2(a, b));
    return *(unsigned int*)&h;
}

// ---------------- K1: W transpose -> bf16 ----------------
__global__ __launch_bounds__(256) void wtrans(
    const float* __restrict__ Wk, const float* __restrict__ Wq,
    const float* __restrict__ Wv, unsigned short* __restrict__ wtg)
{
    int idx = blockIdx.x * 256 + threadIdx.x;     // 0..196607
    int mat = idx >> 16;
    int rem = idx & 65535;
    int h = rem & 63, c = rem >> 6;               // lanes -> h: coalesced reads
    const float* W = (mat == 0) ? Wk : (mat == 1) ? Wq : Wv;
    wtg[(size_t)(mat * 64 + h) * CDIM + c] = f2bf(W[c * HDIM + h]);
}

// ---------------- K2: QKV projection (x + W LDS-staged, reg prefetch) -------
__global__ __launch_bounds__(512) void qkv_proj(
    const float* __restrict__ x, const unsigned short* __restrict__ wtg,
    unsigned short* __restrict__ kg, unsigned short* __restrict__ qg,
    unsigned short* __restrict__ vtg)
{
    __shared__ __align__(16) unsigned short xs[64][72];
    __shared__ __align__(16) unsigned short wts[192][72];
    const int t = threadIdx.x;
    const int lane = t & 63, wv = t >> 6, quad = lane >> 4, l16 = lane & 15;
    const int mp = wv >> 2;                  // m-tiles 2mp, 2mp+1
    const int nq = wv & 3;                   // n-tiles nq*3..nq*3+2
    const int row0 = blockIdx.x * 64;

    const int xr0 = t >> 4,      xc4 = (t & 15) * 4;   // + i*32 rows
    const int wn0 = t >> 3,      wc8 = (t & 7) * 8;    // + i*64 rows

    f32x4 acc[2][3];
    #pragma unroll
    for (int i = 0; i < 2; i++)
        #pragma unroll
        for (int j = 0; j < 3; j++) acc[i][j] = (f32x4){0.f, 0.f, 0.f, 0.f};

    float4 xv0 = *(const float4*)&x[(size_t)(row0 + xr0) * CDIM + xc4];
    float4 xv1 = *(const float4*)&x[(size_t)(row0 + xr0 + 32) * CDIM + xc4];
    us8 w0 = *(const us8*)&wtg[(size_t)(wn0 +   0) * CDIM + wc8];
    us8 w1 = *(const us8*)&wtg[(size_t)(wn0 +  64) * CDIM + wc8];
    us8 w2 = *(const us8*)&wtg[(size_t)(wn0 + 128) * CDIM + wc8];

    for (int cc = 0; cc < CDIM; cc += 64) {
        __syncthreads();
        us4 p0 = { f2bf(xv0.x), f2bf(xv0.y), f2bf(xv0.z), f2bf(xv0.w) };
        us4 p1 = { f2bf(xv1.x), f2bf(xv1.y), f2bf(xv1.z), f2bf(xv1.w) };
        *(us4*)&xs[xr0][xc4] = p0;
        *(us4*)&xs[xr0 + 32][xc4] = p1;
        *(us8*)&wts[wn0 +   0][wc8] = w0;
        *(us8*)&wts[wn0 +  64][wc8] = w1;
        *(us8*)&wts[wn0 + 128][wc8] = w2;
        __syncthreads();
        if (cc + 64 < CDIM) {                  // prefetch next chunk
            int nc = cc + 64;
            xv0 = *(const float4*)&x[(size_t)(row0 + xr0) * CDIM + nc + xc4];
            xv1 = *(const float4*)&x[(size_t)(row0 + xr0 + 32) * CDIM + nc + xc4];
            w0 = *(const us8*)&wtg[(size_t)(wn0 +   0) * CDIM + nc + wc8];
            w1 = *(const us8*)&wtg[(size_t)(wn0 +  64) * CDIM + nc + wc8];
            w2 = *(const us8*)&wtg[(size_t)(wn0 + 128) * CDIM + nc + wc8];
        }
        bf16x8 a[2][2];
        #pragma unroll
        for (int i = 0; i < 2; i++) {
            int mr = (mp * 2 + i) * 16 + l16;
            a[i][0] = *(const bf16x8*)&xs[mr][quad * 8];
            a[i][1] = *(const bf16x8*)&xs[mr][32 + quad * 8];
        }
        #pragma unroll
        for (int j = 0; j < 3; j++) {
            int nt = nq * 3 + j;
            bf16x8 b0 = *(const bf16x8*)&wts[nt * 16 + l16][quad * 8];
            bf16x8 b1 = *(const bf16x8*)&wts[nt * 16 + l16][32 + quad * 8];
            #pragma unroll
            for (int i = 0; i < 2; i++) {
                acc[i][j] = __builtin_amdgcn_mfma_f32_16x16x32_bf16(a[i][0], b0, acc[i][j], 0, 0, 0);
                acc[i][j] = __builtin_amdgcn_mfma_f32_16x16x32_bf16(a[i][1], b1, acc[i][j], 0, 0, 0);
            }
        }
    }

    #pragma unroll
    for (int i = 0; i < 2; i++) {
        const int mrow = row0 + (mp * 2 + i) * 16 + quad * 4;
        #pragma unroll
        for (int j = 0; j < 3; j++) {
            int nt = nq * 3 + j;
            int mat = nt >> 2;
            int col = (nt & 3) * 16 + l16;
            #pragma unroll
            for (int reg = 0; reg < 4; reg++) {
                int r = mrow + reg;
                float val = acc[i][j][reg];
                if (mat == 1) val *= QSCALE;           // pre-scale q
                unsigned short bv = f2bf(val);
                if (mat == 0)      kg[(size_t)r * HDIM + col] = bv;
                else if (mat == 1) qg[(size_t)r * HDIM + col] = bv;
                else {
                    int bb = r >> 12, tr = r & 4095;
                    vtg[((size_t)(bb * HDIM + col) << 12) + tr] = bv;
                }
            }
        }
    }
}

// ---------------- K3: barrier-free chunked attention ----------------
// 128-row Q-tiles, 64-key kt tiles, <=8 tiles per block. Group g=0..7: qts
// 4g..4g+3, g+1 chunks each; 144 blocks/batch, 576 total. Each of the 4 waves
// owns 32 q-rows and walks the chunk's kt tiles independently (no barriers).
__global__ __launch_bounds__(256) void attn(
    const unsigned short* __restrict__ qg, const unsigned short* __restrict__ kg,
    const unsigned short* __restrict__ vtg, float* __restrict__ accp)
{
    __shared__ __align__(16) unsigned short Ps[4][32][72];   // wave-private P

    const int t = threadIdx.x;
    const int lane = t & 63, wv = t >> 6, quad = lane >> 4, l16 = lane & 15;

    const int b = blockIdx.x / 144;
    int s = blockIdx.x - b * 144;
    int g = 0;
    while (2 * (g + 1) * (g + 2) <= s) g++;
    int u = s - 2 * g * (g + 1);
    int qi = 4 * g + u / (g + 1);
    int c  = u - (u / (g + 1)) * (g + 1);

    const size_t bbase = (size_t)b * TDIM;
    const int Q0 = qi * 128;
    const int wrow0 = wv * 32;                 // wave's first q-row in tile
    const int kt0 = c * 8;
    int kt1 = 2 * qi + 1;                      // block's last tile
    int ktw = (Q0 + wrow0 + 31) >> 6;          // wave's own diagonal tile
    if (ktw < kt1) kt1 = ktw;
    if (kt0 + 7 < kt1) kt1 = kt0 + 7;

    // Q fragments (A/B layout: idx=lane&15, k=quad*8+j)
    bf16x8 qa[2][2];
    #pragma unroll
    for (int mt2 = 0; mt2 < 2; mt2++) {
        const unsigned short* qr = qg + (bbase + Q0 + wrow0 + mt2 * 16 + l16) * HDIM;
        qa[mt2][0] = *(const bf16x8*)(qr + quad * 8);
        qa[mt2][1] = *(const bf16x8*)(qr + 32 + quad * 8);
    }

    f32x4 O[2][4];
    #pragma unroll
    for (int mt2 = 0; mt2 < 2; mt2++)
        #pragma unroll
        for (int nt = 0; nt < 4; nt++) O[mt2][nt] = (f32x4){0.f, 0.f, 0.f, 0.f};
    float lsum[2] = {0.f, 0.f};

    const unsigned short* kbase = kg + bbase * HDIM;
    const unsigned short* vbase = vtg + (((size_t)b * HDIM) << 12);

    for (int kt = kt0; kt <= kt1; kt++) {
        // --- K fragments straight from global (L2-resident) ---
        bf16x8 ka[4][2];
        #pragma unroll
        for (int st = 0; st < 4; st++) {
            const unsigned short* kr = kbase + (size_t)(kt * 64 + st * 16 + l16) * HDIM;
            ka[st][0] = *(const bf16x8*)(kr + quad * 8);
            ka[st][1] = *(const bf16x8*)(kr + 32 + quad * 8);
        }
        // --- S^T = K Q^T: C[m=key=quad*4+r][n=qrow=l16] ---
        f32x4 sT[4][2];
        #pragma unroll
        for (int st = 0; st < 4; st++)
            #pragma unroll
            for (int mt2 = 0; mt2 < 2; mt2++) {
                f32x4 z = (f32x4){0.f, 0.f, 0.f, 0.f};
                z = __builtin_amdgcn_mfma_f32_16x16x32_bf16(ka[st][0], qa[mt2][0], z, 0, 0, 0);
                z = __builtin_amdgcn_mfma_f32_16x16x32_bf16(ka[st][1], qa[mt2][1], z, 0, 0, 0);
                sT[st][mt2] = z;
            }
        // --- causal mask (diagonal-touching tiles only; wave-uniform) ---
        if (kt * 64 + 63 > Q0 + wrow0) {
            #pragma unroll
            for (int st = 0; st < 4; st++)
                #pragma unroll
                for (int mt2 = 0; mt2 < 2; mt2++) {
                    int qrow = Q0 + wrow0 + mt2 * 16 + l16;
                    #pragma unroll
                    for (int r = 0; r < 4; r++) {
                        int key = kt * 64 + st * 16 + quad * 4 + r;
                        if (key > qrow) sT[st][mt2][r] = -1e30f;
                    }
                }
        }
        // --- p = exp2(s); pack 4 keys -> b64 LDS write; accumulate l ---
        #pragma unroll
        for (int st = 0; st < 4; st++)
            #pragma unroll
            for (int mt2 = 0; mt2 < 2; mt2++) {
                float p0 = exp2f(sT[st][mt2][0]);
                float p1 = exp2f(sT[st][mt2][1]);
                float p2 = exp2f(sT[st][mt2][2]);
                float p3 = exp2f(sT[st][mt2][3]);
                lsum[mt2] += (p0 + p1) + (p2 + p3);
                uint2 w = make_uint2(pk2bf(p0, p1), pk2bf(p2, p3));
                *(uint2*)&Ps[wv][mt2 * 16 + l16][st * 16 + quad * 4] = w;
            }
        // --- P A-frags from LDS; V B-frags from global; PV MFMAs ---
        bf16x8 pa[2][2];
        #pragma unroll
        for (int mt2 = 0; mt2 < 2; mt2++) {
            pa[mt2][0] = *(const bf16x8*)&Ps[wv][mt2 * 16 + l16][quad * 8];
            pa[mt2][1] = *(const bf16x8*)&Ps[wv][mt2 * 16 + l16][32 + quad * 8];
        }
        #pragma unroll
        for (int nt = 0; nt < 4; nt++) {
            const unsigned short* vr = vbase + (((size_t)(nt * 16 + l16)) << 12) + kt * 64;
            bf16x8 vb0 = *(const bf16x8*)(vr + quad * 8);
            bf16x8 vb1 = *(const bf16x8*)(vr + 32 + quad * 8);
            #pragma unroll
            for (int mt2 = 0; mt2 < 2; mt2++) {
                O[mt2][nt] = __builtin_amdgcn_mfma_f32_16x16x32_bf16(pa[mt2][0], vb0, O[mt2][nt], 0, 0, 0);
                O[mt2][nt] = __builtin_amdgcn_mfma_f32_16x16x32_bf16(pa[mt2][1], vb1, O[mt2][nt], 0, 0, 0);
            }
        }
    }

    // --- flush: O partials (C-layout rows quad*4+r) + l (rows l16) ---
    #pragma unroll
    for (int mt2 = 0; mt2 < 2; mt2++) {
        lsum[mt2] += __shfl_xor(lsum[mt2], 16, 64);
        lsum[mt2] += __shfl_xor(lsum[mt2], 32, 64);
        const int grow = (b << 12) + Q0 + wrow0 + mt2 * 16 + quad * 4;
        #pragma unroll
        for (int nt = 0; nt < 4; nt++)
            #pragma unroll
            for (int r = 0; r < 4; r++)
                atomicAdd(&accp[(size_t)(grow + r) * ACCW + nt * 16 + l16], O[mt2][nt][r]);
        if (quad == 0) {
            int lrow = (b << 12) + Q0 + wrow0 + mt2 * 16 + l16;
            atomicAdd(&accp[(size_t)lrow * ACCW + 64], lsum[mt2]);
        }
    }
}

// ---------------- K4: normalize ----------------
__global__ __launch_bounds__(256) void normalize(
    const float* __restrict__ accp, float* __restrict__ out)
{
    int idx = blockIdx.x * 256 + threadIdx.x;   // 262144
    int row = idx >> 4, c4 = (idx & 15) * 4;
    float inv = 1.f / accp[(size_t)row * ACCW + 64];
    float4 o = *(const float4*)&accp[(size_t)row * ACCW + c4];
    float4 res = make_float4(o.x * inv, o.y * inv, o.z * inv, o.w * inv);
    *(float4*)&out[(size_t)row * HDIM + c4] = res;
}

extern "C" void kernel_launch(void* const* d_in, const int* in_sizes, int n_in,
                              void* d_out, int out_size, void* d_ws, size_t ws_size,
                              hipStream_t stream) {
    const float* x  = (const float*)d_in[0];
    const float* Wk = (const float*)d_in[1];
    const float* Wq = (const float*)d_in[2];
    const float* Wv = (const float*)d_in[3];
    float* out = (float*)d_out;

    unsigned short* wtg = (unsigned short*)d_ws;        // [192][1024] bf16
    unsigned short* kg  = wtg + 196608;                 // [BT][64] bf16
    unsigned short* qg  = kg + (size_t)BT * HDIM;       // [BT][64] bf16 (scaled)
    unsigned short* vtg = qg + (size_t)BT * HDIM;       // [4][64][4096] bf16
    float* accp = (float*)(vtg + (size_t)4 * HDIM * TDIM);  // [BT][68] fp32

    hipMemsetAsync(accp, 0, (size_t)BT * ACCW * sizeof(float), stream);
    wtrans<<<768, 256, 0, stream>>>(Wk, Wq, Wv, wtg);
    qkv_proj<<<BT / 64, 512, 0, stream>>>(x, wtg, kg, qg, vtg);
    attn<<<4 * 144, 256, 0, stream>>>(qg, kg, vtg, accp);
    normalize<<<BT * HDIM / (4 * 256), 256, 0, stream>>>(accp, out);
}

// Round 8
// 160.633 us; speedup vs baseline: 1.1737x; 1.1737x over previous
//
#include <hip/hip_runtime.h>
#include <hip/hip_bf16.h>
#include <math.h>

// B=4, T=4096, C=1024, H=64. fp32 in/out, bf16 MFMA internally.
// memset: zero accp (fp32 accumulator [BT][68], col 64 = l).
// K1 wtrans: W (C,H) fp32 -> WT bf16 [192][1024], LDS-tile transpose
//            (coalesced reads AND writes).
// K2 qkv_proj: M=64/block, grid 256, 512 thr; x+W LDS-staged, reg prefetch.
// K3 attn: barriered LDS staging (round-6 structure: the only one that
//     doesn't eat L2 latency) + round-7 wins: S computed TRANSPOSED
//     (mfma(K,Q) -> packed b64 P writes), l accumulated in-register.
//     64-row Q-tiles, <=8 kt-tiles per chunk, 1152 blocks, 27.6 KB LDS
//     -> 5 blocks/CU resident (barrier overlap across blocks).
// K4 normalize: out = acc[:, :64] / acc[:, 64].

#define BT   16384
#define TDIM 4096
#define CDIM 1024
#define HDIM 64
#define ACCW 68
#define QSCALE 0.18033688f   // 0.125 * log2(e)

typedef __attribute__((ext_vector_type(8))) short bf16x8;
typedef __attribute__((ext_vector_type(4))) float f32x4;
typedef __attribute__((ext_vector_type(8))) unsigned short us8;
typedef __attribute__((ext_vector_type(4))) unsigned short us4;

static __device__ __forceinline__ unsigned short f2bf(float f) {
    unsigned int u = __float_as_uint(f);
    u += 0x7fffu + ((u >> 16) & 1u);
    return (unsigned short)(u >> 16);
}

static __device__ __forceinline__ unsigned int pk2bf(float a, float b) {
    __hip_bfloat162 h = __float22bfloat162_rn(make_float2(a, b));
    return *(unsigned int*)&h;
}

// ---------------- K1: W transpose -> bf16 (LDS tile, both sides coalesced) --
__global__ __launch_bounds__(256) void wtrans(
    const float* __restrict__ Wk, const float* __restrict__ Wq,
    const float* __restrict__ Wv, unsigned short* __restrict__ wtg)
{
    __shared__ float tile[64][65];
    const int mat = blockIdx.x >> 4, ct = blockIdx.x & 15;
    const float* W = (mat == 0) ? Wk : (mat == 1) ? Wq : Wv;
    const int c0 = ct * 64;
    const int t = threadIdx.x;
    #pragma unroll
    for (int p = 0; p < 4; p++) {          // 64 c-rows x 64 h, float4 reads
        int idx = p * 256 + t;
        int c = idx >> 4, h4 = (idx & 15) * 4;
        float4 v = *(const float4*)&W[(size_t)(c0 + c) * HDIM + h4];
        tile[c][h4] = v.x; tile[c][h4 + 1] = v.y;
        tile[c][h4 + 2] = v.z; tile[c][h4 + 3] = v.w;
    }
    __syncthreads();
    #pragma unroll
    for (int p = 0; p < 2; p++) {          // 64 h-rows x 64 c, us8 writes
        int idx = p * 256 + t;
        int h = idx >> 3, c8 = (idx & 7) * 8;
        us8 o;
        #pragma unroll
        for (int j = 0; j < 8; j++) o[j] = f2bf(tile[c8 + j][h]);
        *(us8*)&wtg[(size_t)(mat * 64 + h) * CDIM + c0 + c8] = o;
    }
}

// ---------------- K2: QKV projection (x + W LDS-staged, reg prefetch) -------
__global__ __launch_bounds__(512) void qkv_proj(
    const float* __restrict__ x, const unsigned short* __restrict__ wtg,
    unsigned short* __restrict__ kg, unsigned short* __restrict__ qg,
    unsigned short* __restrict__ vtg)
{
    __shared__ __align__(16) unsigned short xs[64][72];
    __shared__ __align__(16) unsigned short wts[192][72];
    const int t = threadIdx.x;
    const int lane = t & 63, wv = t >> 6, quad = lane >> 4, l16 = lane & 15;
    const int mp = wv >> 2;                  // m-tiles 2mp, 2mp+1
    const int nq = wv & 3;                   // n-tiles nq*3..nq*3+2
    const int row0 = blockIdx.x * 64;

    const int xr0 = t >> 4,      xc4 = (t & 15) * 4;   // + i*32 rows
    const int wn0 = t >> 3,      wc8 = (t & 7) * 8;    // + i*64 rows

    f32x4 acc[2][3];
    #pragma unroll
    for (int i = 0; i < 2; i++)
        #pragma unroll
        for (int j = 0; j < 3; j++) acc[i][j] = (f32x4){0.f, 0.f, 0.f, 0.f};

    float4 xv0 = *(const float4*)&x[(size_t)(row0 + xr0) * CDIM + xc4];
    float4 xv1 = *(const float4*)&x[(size_t)(row0 + xr0 + 32) * CDIM + xc4];
    us8 w0 = *(const us8*)&wtg[(size_t)(wn0 +   0) * CDIM + wc8];
    us8 w1 = *(const us8*)&wtg[(size_t)(wn0 +  64) * CDIM + wc8];
    us8 w2 = *(const us8*)&wtg[(size_t)(wn0 + 128) * CDIM + wc8];

    for (int cc = 0; cc < CDIM; cc += 64) {
        __syncthreads();
        us4 p0 = { f2bf(xv0.x), f2bf(xv0.y), f2bf(xv0.z), f2bf(xv0.w) };
        us4 p1 = { f2bf(xv1.x), f2bf(xv1.y), f2bf(xv1.z), f2bf(xv1.w) };
        *(us4*)&xs[xr0][xc4] = p0;
        *(us4*)&xs[xr0 + 32][xc4] = p1;
        *(us8*)&wts[wn0 +   0][wc8] = w0;
        *(us8*)&wts[wn0 +  64][wc8] = w1;
        *(us8*)&wts[wn0 + 128][wc8] = w2;
        __syncthreads();
        if (cc + 64 < CDIM) {                  // prefetch next chunk
            int nc = cc + 64;
            xv0 = *(const float4*)&x[(size_t)(row0 + xr0) * CDIM + nc + xc4];
            xv1 = *(const float4*)&x[(size_t)(row0 + xr0 + 32) * CDIM + nc + xc4];
            w0 = *(const us8*)&wtg[(size_t)(wn0 +   0) * CDIM + nc + wc8];
            w1 = *(const us8*)&wtg[(size_t)(wn0 +  64) * CDIM + nc + wc8];
            w2 = *(const us8*)&wtg[(size_t)(wn0 + 128) * CDIM + nc + wc8];
        }
        bf16x8 a[2][2];
        #pragma unroll
        for (int i = 0; i < 2; i++) {
            int mr = (mp * 2 + i) * 16 + l16;
            a[i][0] = *(const bf16x8*)&xs[mr][quad * 8];
            a[i][1] = *(const bf16x8*)&xs[mr][32 + quad * 8];
        }
        #pragma unroll
        for (int j = 0; j < 3; j++) {
            int nt = nq * 3 + j;
            bf16x8 b0 = *(const bf16x8*)&wts[nt * 16 + l16][quad * 8];
            bf16x8 b1 = *(const bf16x8*)&wts[nt * 16 + l16][32 + quad * 8];
            #pragma unroll
            for (int i = 0; i < 2; i++) {
                acc[i][j] = __builtin_amdgcn_mfma_f32_16x16x32_bf16(a[i][0], b0, acc[i][j], 0, 0, 0);
                acc[i][j] = __builtin_amdgcn_mfma_f32_16x16x32_bf16(a[i][1], b1, acc[i][j], 0, 0, 0);
            }
        }
    }

    #pragma unroll
    for (int i = 0; i < 2; i++) {
        const int mrow = row0 + (mp * 2 + i) * 16 + quad * 4;
        #pragma unroll
        for (int j = 0; j < 3; j++) {
            int nt = nq * 3 + j;
            int mat = nt >> 2;
            int col = (nt & 3) * 16 + l16;
            #pragma unroll
            for (int reg = 0; reg < 4; reg++) {
                int r = mrow + reg;
                float val = acc[i][j][reg];
                if (mat == 1) val *= QSCALE;           // pre-scale q
                unsigned short bv = f2bf(val);
                if (mat == 0)      kg[(size_t)r * HDIM + col] = bv;
                else if (mat == 1) qg[(size_t)r * HDIM + col] = bv;
                else {
                    int bb = r >> 12, tr = r & 4095;
                    vtg[((size_t)(bb * HDIM + col) << 12) + tr] = bv;
                }
            }
        }
    }
}

// ---------------- K3: barriered attention, S^T + packed P, 64-row tiles -----
// Per batch: qt=0..63, ceil((qt+1)/8) chunks; group g=0..7 covers qt 8g..8g+7
// with g+1 chunks each -> 8(g+1) blocks, cum 4g(g+1); 288/batch, 1152 total.
__global__ __launch_bounds__(256) void attn(
    const unsigned short* __restrict__ qg, const unsigned short* __restrict__ kg,
    const unsigned short* __restrict__ vtg, float* __restrict__ accp)
{
    __shared__ __align__(16) unsigned short Ks[64][72];
    __shared__ __align__(16) unsigned short Vt[64][72];
    __shared__ __align__(16) unsigned short Ps[4][16][72];

    const int t = threadIdx.x;
    const int lane = t & 63, wv = t >> 6, quad = lane >> 4, l16 = lane & 15;

    const int b = blockIdx.x / 288;
    int s = blockIdx.x - b * 288;
    int g = 0;
    while (4 * (g + 1) * (g + 2) <= s) g++;
    int u = s - 4 * g * (g + 1);
    int qt = 8 * g + u / (g + 1);
    int c  = u - (u / (g + 1)) * (g + 1);

    const size_t bbase = (size_t)b * TDIM;
    const int Q0 = qt * 64;
    const int kt0 = c * 8;
    const int kt1 = (kt0 + 7 < qt) ? kt0 + 7 : qt;

    // Q B-frags (n = l16 -> qrow, k = quad*8+j)
    const int qrow = Q0 + wv * 16 + l16;
    const unsigned short* qr = qg + (bbase + qrow) * HDIM;
    bf16x8 qa0 = *(const bf16x8*)(qr + quad * 8);
    bf16x8 qa1 = *(const bf16x8*)(qr + 32 + quad * 8);

    f32x4 O[4];
    #pragma unroll
    for (int nt = 0; nt < 4; nt++) O[nt] = (f32x4){0.f, 0.f, 0.f, 0.f};
    float lsum = 0.f;

    const int fr = t >> 3, fc = (t & 7) * 8;     // staging rows fr, fr+32

    us8 kr0 = *(const us8*)&kg[(bbase + kt0 * 64 + fr) * HDIM + fc];
    us8 kr1 = *(const us8*)&kg[(bbase + kt0 * 64 + fr + 32) * HDIM + fc];
    us8 vr0 = *(const us8*)&vtg[((size_t)(b * HDIM + fr) << 12) + kt0 * 64 + fc];
    us8 vr1 = *(const us8*)&vtg[((size_t)(b * HDIM + fr + 32) << 12) + kt0 * 64 + fc];

    const int wlast = Q0 + wv * 16 + 15;         // wave's last q-row

    for (int kt = kt0; kt <= kt1; kt++) {
        __syncthreads();                          // prev readers done
        *(us8*)&Ks[fr][fc] = kr0;
        *(us8*)&Ks[fr + 32][fc] = kr1;
        *(us8*)&Vt[fr][fc] = vr0;
        *(us8*)&Vt[fr + 32][fc] = vr1;
        __syncthreads();
        if (kt < kt1) {                           // prefetch next tile
            int kn = kt + 1;
            kr0 = *(const us8*)&kg[(bbase + kn * 64 + fr) * HDIM + fc];
            kr1 = *(const us8*)&kg[(bbase + kn * 64 + fr + 32) * HDIM + fc];
            vr0 = *(const us8*)&vtg[((size_t)(b * HDIM + fr) << 12) + kn * 64 + fc];
            vr1 = *(const us8*)&vtg[((size_t)(b * HDIM + fr + 32) << 12) + kn * 64 + fc];
        }
        if (kt * 64 > wlast) continue;            // tile fully masked for wave

        // --- S^T = K Q^T: C[m=key=quad*4+r][n=qrow=l16] ---
        f32x4 sT[4];
        #pragma unroll
        for (int st = 0; st < 4; st++) {
            bf16x8 ka0 = *(const bf16x8*)&Ks[st * 16 + l16][quad * 8];
            bf16x8 ka1 = *(const bf16x8*)&Ks[st * 16 + l16][32 + quad * 8];
            f32x4 z = (f32x4){0.f, 0.f, 0.f, 0.f};
            z = __builtin_amdgcn_mfma_f32_16x16x32_bf16(ka0, qa0, z, 0, 0, 0);
            z = __builtin_amdgcn_mfma_f32_16x16x32_bf16(ka1, qa1, z, 0, 0, 0);
            sT[st] = z;
        }
        // --- causal mask (only diagonal-touching tiles) ---
        if (kt * 64 + 63 > Q0 + wv * 16) {
            #pragma unroll
            for (int st = 0; st < 4; st++)
                #pragma unroll
                for (int r = 0; r < 4; r++) {
                    int key = kt * 64 + st * 16 + quad * 4 + r;
                    if (key > qrow) sT[st][r] = -1e30f;
                }
        }
        // --- p = exp2(s); pack 4 keys -> b64 write; accumulate l ---
        #pragma unroll
        for (int st = 0; st < 4; st++) {
            float p0 = exp2f(sT[st][0]);
            float p1 = exp2f(sT[st][1]);
            float p2 = exp2f(sT[st][2]);
            float p3 = exp2f(sT[st][3]);
            lsum += (p0 + p1) + (p2 + p3);
            uint2 w = make_uint2(pk2bf(p0, p1), pk2bf(p2, p3));
            *(uint2*)&Ps[wv][l16][st * 16 + quad * 4] = w;
        }
        // --- O += P V: P A-frag from wave-private LDS, V B-frag from LDS ---
        bf16x8 pa0 = *(const bf16x8*)&Ps[wv][l16][quad * 8];
        bf16x8 pa1 = *(const bf16x8*)&Ps[wv][l16][32 + quad * 8];
        #pragma unroll
        for (int nt = 0; nt < 4; nt++) {
            bf16x8 vb0 = *(const bf16x8*)&Vt[nt * 16 + l16][quad * 8];
            bf16x8 vb1 = *(const bf16x8*)&Vt[nt * 16 + l16][32 + quad * 8];
            O[nt] = __builtin_amdgcn_mfma_f32_16x16x32_bf16(pa0, vb0, O[nt], 0, 0, 0);
            O[nt] = __builtin_amdgcn_mfma_f32_16x16x32_bf16(pa1, vb1, O[nt], 0, 0, 0);
        }
    }

    // --- flush: O (C rows quad*4+r) + l (row l16, sum over quads) ---
    lsum += __shfl_xor(lsum, 16, 64);
    lsum += __shfl_xor(lsum, 32, 64);
    const int grow = (b << 12) + Q0 + wv * 16 + quad * 4;
    #pragma unroll
    for (int nt = 0; nt < 4; nt++)
        #pragma unroll
        for (int r = 0; r < 4; r++)
            atomicAdd(&accp[(size_t)(grow + r) * ACCW + nt * 16 + l16], O[nt][r]);
    if (quad == 0)
        atomicAdd(&accp[(size_t)((b << 12) + qrow) * ACCW + 64], lsum);
}

// ---------------- K4: normalize ----------------
__global__ __launch_bounds__(256) void normalize(
    const float* __restrict__ accp, float* __restrict__ out)
{
    int idx = blockIdx.x * 256 + threadIdx.x;   // 262144
    int row = idx >> 4, c4 = (idx & 15) * 4;
    float inv = 1.f / accp[(size_t)row * ACCW + 64];
    float4 o = *(const float4*)&accp[(size_t)row * ACCW + c4];
    float4 res = make_float4(o.x * inv, o.y * inv, o.z * inv, o.w * inv);
    *(float4*)&out[(size_t)row * HDIM + c4] = res;
}

extern "C" void kernel_launch(void* const* d_in, const int* in_sizes, int n_in,
                              void* d_out, int out_size, void* d_ws, size_t ws_size,
                              hipStream_t stream) {
    const float* x  = (const float*)d_in[0];
    const float* Wk = (const float*)d_in[1];
    const float* Wq = (const float*)d_in[2];
    const float* Wv = (const float*)d_in[3];
    float* out = (float*)d_out;

    unsigned short* wtg = (unsigned short*)d_ws;        // [192][1024] bf16
    unsigned short* kg  = wtg + 196608;                 // [BT][64] bf16
    unsigned short* qg  = kg + (size_t)BT * HDIM;       // [BT][64] bf16 (scaled)
    unsigned short* vtg = qg + (size_t)BT * HDIM;       // [4][64][4096] bf16
    float* accp = (float*)(vtg + (size_t)4 * HDIM * TDIM);  // [BT][68] fp32

    hipMemsetAsync(accp, 0, (size_t)BT * ACCW * sizeof(float), stream);
    wtrans<<<48, 256, 0, stream>>>(Wk, Wq, Wv, wtg);
    qkv_proj<<<BT / 64, 512, 0, stream>>>(x, wtg, kg, qg, vtg);
    attn<<<4 * 288, 256, 0, stream>>>(qg, kg, vtg, accp);
    normalize<<<BT * HDIM / (4 * 256), 256, 0, stream>>>(accp, out);
}